// Round 17
// baseline (90.235 us; speedup 1.0000x reference)
//
#include <hip/hip_runtime.h>
#include <hip/hip_bf16.h>
#include <math.h>

#define BB 8
#define HH 64
#define WW 64
#define CINC 32
#define COUTC 64
#define KK 8
#define VSN 12
#define HIDDEN 128
#define ADIN 34
#define PXB 16           // pixels per block
#define FPAD 260         // padded sFeat row stride (floats)
#define W2S 132          // packed W2T row stride (floats)

typedef short short8 __attribute__((ext_vector_type(8)));
typedef float f32x4 __attribute__((ext_vector_type(4)));

__device__ __forceinline__ short f2bfs(float f) {
    __hip_bfloat16 h = __float2bfloat16(f);   // RNE
    return __builtin_bit_cast(short, h);
}
__device__ __forceinline__ float bfs2f(short s) {
    return __bfloat162float(__builtin_bit_cast(__hip_bfloat16, s));
}

// Fused prep:
//   blocks [0,512)   : tiled transpose x (B,CIN,H,W) -> xf (B,HW,CIN)
//   blocks [512,576) : split Wu into bf16 hi/lo MFMA-B-fragment order
//   blocks [576,589) : pack W2 (128,24) -> W2T (24,132) f32, zero-padded
__global__ __launch_bounds__(256) void prep_all(const float* __restrict__ x,
                                                const float* __restrict__ Wu,
                                                const float* __restrict__ W2,
                                                float* __restrict__ xf,
                                                short* __restrict__ bs,
                                                float* __restrict__ w2t) {
    int bid = blockIdx.x;
    if (bid < 512) {
        __shared__ float tile[32][65];   // +1 pad
        int b    = bid >> 6;             // 8 b
        int pos0 = (bid & 63) << 6;      // 64-pos tile
        int t    = threadIdx.x;
        #pragma unroll
        for (int it = 0; it < 2; ++it) {
            int idx = t + (it << 8);
            int c   = idx >> 4;
            int p4  = idx & 15;
            float4 v = *(const float4*)&x[(((b << 5) + c) << 12) + pos0 + (p4 << 2)];
            tile[c][(p4 << 2) + 0] = v.x;
            tile[c][(p4 << 2) + 1] = v.y;
            tile[c][(p4 << 2) + 2] = v.z;
            tile[c][(p4 << 2) + 3] = v.w;
        }
        __syncthreads();
        #pragma unroll
        for (int it = 0; it < 2; ++it) {
            int idx = t + (it << 8);
            int p   = idx >> 3;
            int c4  = idx & 7;
            float4 v;
            v.x = tile[(c4 << 2) + 0][p];
            v.y = tile[(c4 << 2) + 1][p];
            v.z = tile[(c4 << 2) + 2][p];
            v.w = tile[(c4 << 2) + 3][p];
            *(float4*)&xf[(((b << 12) + pos0 + p) << 5) + (c4 << 2)] = v;
        }
    } else if (bid < 576) {
        int tid = (bid - 512) * 256 + threadIdx.x;   // 0..16383
        int r = tid >> 6, c = tid & 63;
        float f  = Wu[tid];
        short hi = f2bfs(f);
        short lo = f2bfs(f - bfs2f(hi));
        int s = r >> 5, r5 = r & 31, kg = r5 >> 3, j = r5 & 7;
        int base = ((((s << 2) + kg) << 6) | c) << 4;
        bs[base + j]     = hi;
        bs[base + 8 + j] = lo;
    } else {
        int tid = (bid - 576) * 256 + threadIdx.x;   // 0..3327
        if (tid < 24 * W2S) {
            int o = tid / W2S, u = tid - o * W2S;
            w2t[tid] = (u < HIDDEN) ? W2[u * 24 + o] : 0.0f;
        }
    }
}

__global__ __launch_bounds__(512, 6) void fused2v(
    const float* __restrict__ x,   const float* __restrict__ xf,
    const float* __restrict__ W1,  const float* __restrict__ b1,
    const float* __restrict__ W2,  const float* __restrict__ W2T,
    const float* __restrict__ b2,
    const float* __restrict__ Wu,  const short* __restrict__ bs,
    const float* __restrict__ bu,
    const int*  __restrict__ gidx, const int* __restrict__ loff,
    float*      __restrict__ out,  int use_ws)
{
    // LDS map (round-16 minus sW2T; 33536 B -> 4 blocks/CU):
    //   [0,16640)    : sFeat f32[16][260]   (P5/P6) -- overlays sInp/sH/sP
    //     [0,2176)     : sInp f32[16][34]   (P1-P2)
    //     [2176,10368) : sH   f32[16][128]  (P2-P3)
    //     [10368,11904): sP   f32[16][24]   (P3-P4)
    //   [16640,22784): sFlat i32[16][8][12]
    //   [22784,28928): sProp f32[16][8][12]
    //   [28928,29440): sInv  f32[16][8]
    //   [29440,33536): sPart f32[256][4]    (P6 cross-wave partial acc)
    __shared__ __align__(16) char lds[33536];
    float* sFeat = (float*)lds;
    float* sInp  = (float*)lds;
    float* sH    = (float*)(lds + 2176);
    float* sP    = (float*)(lds + 10368);
    int*   sFlat = (int*)  (lds + 16640);
    float* sProp = (float*)(lds + 22784);
    float* sInv  = (float*)(lds + 28928);
    float* sPart = (float*)(lds + 29440);

    const int t    = threadIdx.x;
    const int w    = t >> 6;        // wave 0..7 (two pixels each)
    const int wl   = t & 63;
    const int pix0 = blockIdx.x * PXB;
    const int b    = pix0 >> 12;
    const int rem0 = pix0 & 4095;   // 16 consecutive pixels, same b
    const int w2   = w << 1;        // first local pixel of this wave

    // ---- P1: cooperative input staging ----
    {
        int c  = t & 31;
        int lp = t >> 5;            // 0..15
        int rem = rem0 + lp;
        sInp[lp * ADIN + c] = use_ws ? xf[(((b << 12) + rem) << 5) + c]
                                     : x[(((b << 5) + c) << 12) + rem];
        if (t < PXB) {
            int rem2 = rem0 + t;
            sInp[t * ADIN + 32] = (float)(rem2 >> 6) / 63.0f;
            sInp[t * ADIN + 33] = (float)(rem2 & 63) / 63.0f;
        }
    }
    __syncthreads();

    // ---- P2: hidden = relu(inp @ W1 + b1), 2 pixels/wave ----
    // FROZEN FORM: scalar W1 loads, sequential fmaf chain. Rounds 12/13
    // proved any load-shape restructure here perturbs codegen (fast-math
    // reassociation) -> sP drift -> floor flips -> absmax ~0.86. Do not touch.
    {
        float h0[2], h1[2];
        float bb0 = b1[wl], bb1 = b1[wl + 64];
        #pragma unroll
        for (int q = 0; q < 2; ++q) { h0[q] = bb0; h1[q] = bb1; }
        #pragma unroll 2
        for (int a = 0; a < ADIN; ++a) {
            float wa = W1[a * HIDDEN + wl];
            float wb = W1[a * HIDDEN + wl + 64];
            #pragma unroll
            for (int q = 0; q < 2; ++q) {
                float iv = sInp[(w2 + q) * ADIN + a];
                h0[q] = fmaf(iv, wa, h0[q]);
                h1[q] = fmaf(iv, wb, h1[q]);
            }
        }
        #pragma unroll
        for (int q = 0; q < 2; ++q) {
            sH[(w2 + q) * HIDDEN + wl]      = fmaxf(h0[q], 0.f);
            sH[(w2 + q) * HIDDEN + wl + 64] = fmaxf(h1[q], 0.f);
        }
    }
    // sH rows wave-private: in-wave LDS ordering suffices (round-5/8/9/11-proven)

    // ---- P3: params = hidden @ W2 + b2; W2T read from global (L1-resident) ----
    // FROZEN FORM: sequential single accumulator, float4 chain textually
    // identical to round-9..16 (load source LDS->global is the one proven-safe
    // transform here: round 9 changed it with absmax bit-identical).
    if (wl < 48) {
        int hi = (wl >= 24) ? 1 : 0;
        int o  = wl - (hi ? 24 : 0);
        int lp = w2 + hi;
        float acc = b2[o];
        const float* hrow = &sH[lp * HIDDEN];
        if (use_ws) {
            const float* wrow = &W2T[o * W2S];
            #pragma unroll 8
            for (int u4 = 0; u4 < 32; ++u4) {
                float4 wv = *(const float4*)&wrow[u4 << 2];
                float4 hv = *(const float4*)&hrow[u4 << 2];
                acc = fmaf(hv.x, wv.x, acc);
                acc = fmaf(hv.y, wv.y, acc);
                acc = fmaf(hv.z, wv.z, acc);
                acc = fmaf(hv.w, wv.w, acc);
            }
        } else {
            #pragma unroll 4
            for (int u = 0; u < HIDDEN; ++u)
                acc = fmaf(hrow[u], W2[u * 24 + o], acc);
        }
        sP[lp * 24 + o] = acc;
    }
    // sP rows wave-private

    const int k   = wl >> 3;
    const int sub = wl & 7;

    // ---- P4: gaussian params, sample indices, props, dup, norm ----
    #pragma unroll
    for (int q = 0; q < 2; ++q) {
        int lp  = w2 + q;
        int rem = rem0 + lp;
        int pix = pix0 + lp;
        int i   = rem >> 6, j = rem & 63;

        float mr0 = sP[lp * 24 + 2 * k];
        float mr1 = sP[lp * 24 + 2 * k + 1];
        float sr  = sP[lp * 24 + 16 + k];

        float mid0 = ((float)i / 63.0f) * 63.0f;
        float mid1 = ((float)j / 63.0f) * 63.0f;
        float m0 = fmodf(mid0 + mr0, 63.0f); if (m0 < 0.f) m0 += 63.0f;
        float m1 = fmodf(mid1 + mr1, 63.0f); if (m1 < 0.f) m1 += 63.0f;

        float sx  = sr + 2.0f;                                     // SIGMA_BOOST
        float spv = fmaxf(sx, 0.f) + log1pf(__expf(-fabsf(sx)));   // softplus
        float sig = ((spv + 0.05f) * 63.0f) * 0.05f;
        float isig = 1.0f / sig;    // continuous path only: div-once, mul-per-z

        int fl0 = (int)floorf(m0);
        int fl1 = (int)floorf(m1);
        const int glb = (pix * KK + k) << 3;
        const int fpb = (lp * KK + k) * VSN;

        #pragma unroll
        for (int tt = 0; tt < 2; ++tt) {
            if (tt == 1 && sub >= 4) break;
            int v = (tt == 0) ? sub : 8 + sub;
            int i0, j0;
            if (v < 4) {
                i0 = (fl0 + (v >> 1)) & 63;
                j0 = (fl1 + (v & 1)) & 63;
            } else if (v < 8) {
                int g = (v - 4) << 1;
                i0 = gidx[glb + g];
                j0 = gidx[glb + g + 1];
            } else {
                int r = (v - 8) << 1;
                i0 = (fl0 + loff[glb + r]     - 8 + 64) & 63;
                j0 = (fl1 + loff[glb + r + 1] - 8 + 64) & 63;
            }
            float z0 = ((float)i0 - m0) * isig;
            float z1 = ((float)j0 - m1) * isig;
            sFlat[fpb + v] = i0 * 64 + j0;
            sProp[fpb + v] = __expf(-0.5f * (z0 * z0 + z1 * z1));
        }
        // dup-zero (in-wave cross-lane, round-5/8/9/11-proven idiom)
        #pragma unroll
        for (int tt = 0; tt < 2; ++tt) {
            if (tt == 1 && sub >= 4) break;
            int v = (tt == 0) ? sub : 8 + sub;
            int f = sFlat[fpb + v];
            bool dup = false;
            for (int v2 = 0; v2 < v; ++v2)
                dup |= (sFlat[fpb + v2] == f);
            if (dup) sProp[fpb + v] = 0.0f;
        }
        if (sub == 0) {
            float s = 0.0f;
            #pragma unroll
            for (int v = 0; v < VSN; ++v) s += sProp[fpb + v];
            sInv[lp * KK + k] = 1.0f / s;
        }
    }
    __syncthreads();   // overlay guard: region-A reads done before sFeat writes

    // ---- P5: gather + weighted sum -> sFeat[lp][k*32+c] ----
    #pragma unroll
    for (int q = 0; q < 2; ++q) {
        int lp  = w2 + q;
        const int fpb = (lp * KK + k) * VSN;
        float isum = sInv[lp * KK + k];
        int c4 = sub << 2;
        float a0 = 0.f, a1 = 0.f, a2 = 0.f, a3 = 0.f;
        #pragma unroll
        for (int v = 0; v < VSN; ++v) {
            float wt = sProp[fpb + v] * isum;
            int p = sFlat[fpb + v];
            if (use_ws) {
                const float4 xv = *(const float4*)&xf[(((b << 12) + p) << 5) + c4];
                a0 = fmaf(wt, xv.x, a0);
                a1 = fmaf(wt, xv.y, a1);
                a2 = fmaf(wt, xv.z, a2);
                a3 = fmaf(wt, xv.w, a3);
            } else {
                const float* xb = x + (((b << 5) + c4) << 12) + p;
                a0 = fmaf(wt, xb[0],       a0);
                a1 = fmaf(wt, xb[1 << 12], a1);
                a2 = fmaf(wt, xb[2 << 12], a2);
                a3 = fmaf(wt, xb[3 << 12], a3);
            }
        }
        float4 fv; fv.x = a0; fv.y = a1; fv.z = a2; fv.w = a3;
        *(float4*)&sFeat[lp * FPAD + (k << 5) + c4] = fv;
    }
    __syncthreads();

    // ---- P6: GEMM split across wave pairs, partials reduced via sPart ----
    {
        const int l15 = wl & 15;
        const int kg  = wl >> 4;
        const int sg  = w >> 2;          // 0: s=0..3, 1: s=4..7
        const int wc  = w & 3;
        const int col = (wc << 4) + l15;
        f32x4 acc = {0.f, 0.f, 0.f, 0.f};
        #pragma unroll 1
        for (int s0 = 0; s0 < 4; ++s0) {
            int s = (sg << 2) + s0;
            const float* ap = &sFeat[l15 * FPAD + (s << 5) + (kg << 3)];
            float fa[8];
            *(float4*)&fa[0] = *(const float4*)(ap);
            *(float4*)&fa[4] = *(const float4*)(ap + 4);
            short8 ah, al;
            #pragma unroll
            for (int jj = 0; jj < 8; ++jj) {
                float f = fa[jj];
                short h = f2bfs(f);
                ah[jj] = h;
                al[jj] = f2bfs(f - bfs2f(h));
            }
            short8 bh, bl;
            if (use_ws) {
                const short8* bp =
                    (const short8*)(bs + (((((s << 2) + kg) << 6) | col) << 4));
                bh = bp[0];
                bl = bp[1];
            } else {
                #pragma unroll
                for (int jj = 0; jj < 8; ++jj) {
                    float f = Wu[(((s << 5) + (kg << 3) + jj) << 6) + col];
                    short h = f2bfs(f);
                    bh[jj] = h;
                    bl[jj] = f2bfs(f - bfs2f(h));
                }
            }
            acc = __builtin_amdgcn_mfma_f32_16x16x32_bf16(ah, bh, acc, 0, 0, 0);
            acc = __builtin_amdgcn_mfma_f32_16x16x32_bf16(ah, bl, acc, 0, 0, 0);
            acc = __builtin_amdgcn_mfma_f32_16x16x32_bf16(al, bh, acc, 0, 0, 0);
        }
        if (sg == 1)
            *(f32x4*)&sPart[(t - 256) << 2] = acc;
        __syncthreads();   // uniform: all 512 threads reach this
        if (sg == 0) {
            const f32x4 other = *(const f32x4*)&sPart[t << 2];
            float bub = bu[col];
            float4 ov;
            ov.x = acc[0] + other[0] + bub;
            ov.y = acc[1] + other[1] + bub;
            ov.z = acc[2] + other[2] + bub;
            ov.w = acc[3] + other[3] + bub;
            *(float4*)&out[(((b << 6) + col) << 12) + rem0 + (kg << 2)] = ov;
        }
    }
}

extern "C" void kernel_launch(void* const* d_in, const int* in_sizes, int n_in,
                              void* d_out, int out_size, void* d_ws, size_t ws_size,
                              hipStream_t stream) {
    const float* x    = (const float*)d_in[0];
    const float* W1   = (const float*)d_in[1];
    const float* b1   = (const float*)d_in[2];
    const float* W2   = (const float*)d_in[3];
    const float* b2   = (const float*)d_in[4];
    const float* Wu   = (const float*)d_in[5];
    const float* bu   = (const float*)d_in[6];
    const int*   gidx = (const int*)d_in[7];
    const int*   loff = (const int*)d_in[8];
    float* outp = (float*)d_out;

    const size_t xf_bytes  = (size_t)BB * HH * WW * CINC * 4;   // 4 MiB
    const size_t bs_bytes  = (size_t)256 * 64 * 2 * 2;          // 64 KiB
    const size_t w2t_bytes = (size_t)24 * W2S * 4;              // 12672 B
    int use_ws = (ws_size >= xf_bytes + bs_bytes + w2t_bytes) ? 1 : 0;

    char*  base = (char*)d_ws;
    float* xfp  = (float*)base;
    short* bsp  = (short*)(base + xf_bytes);
    float* w2tp = (float*)(base + xf_bytes + bs_bytes);

    if (use_ws) {
        // fused prep: 512 transpose + 64 pack_wu + 13 pack_w2t blocks
        prep_all<<<512 + 64 + 13, 256, 0, stream>>>(x, Wu, W2, xfp, bsp, w2tp);
    }
    fused2v<<<(BB * HH * WW) / PXB, 512, 0, stream>>>(
        x, xfp, W1, b1, W2, w2tp, b2, Wu, bsp, bu, gidx, loff, outp, use_ws);
}

// Round 18
// 78.401 us; speedup vs baseline: 1.1509x; 1.1509x over previous
//
#include <hip/hip_runtime.h>
#include <hip/hip_bf16.h>
#include <math.h>

#define BB 8
#define HH 64
#define WW 64
#define CINC 32
#define COUTC 64
#define KK 8
#define VSN 12
#define HIDDEN 128
#define ADIN 34
#define PXB 16           // pixels per block
#define FPAD 260         // padded sFeat row stride (floats)
#define W2S 132          // padded W2T row stride (floats)

typedef short short8 __attribute__((ext_vector_type(8)));
typedef float f32x4 __attribute__((ext_vector_type(4)));

__device__ __forceinline__ short f2bfs(float f) {
    __hip_bfloat16 h = __float2bfloat16(f);   // RNE
    return __builtin_bit_cast(short, h);
}
__device__ __forceinline__ float bfs2f(short s) {
    return __bfloat162float(__builtin_bit_cast(__hip_bfloat16, s));
}

// Fused prep:
//   blocks [0,512)   : tiled transpose x (B,CIN,H,W) -> xf (B,HW,CIN)
//                      (32c x 64pos tile via LDS, float4 coalesced both sides)
//   blocks [512,576) : split Wu into bf16 hi/lo MFMA-B-fragment order
__global__ __launch_bounds__(256) void prep_all(const float* __restrict__ x,
                                                const float* __restrict__ Wu,
                                                float* __restrict__ xf,
                                                short* __restrict__ bs) {
    int bid = blockIdx.x;
    if (bid < 512) {
        __shared__ float tile[32][65];   // +1 pad: store-side reads ~2-way max
        int b    = bid >> 6;             // 8 b
        int pos0 = (bid & 63) << 6;      // 64-pos tile
        int t    = threadIdx.x;
        #pragma unroll
        for (int it = 0; it < 2; ++it) {
            int idx = t + (it << 8);     // 0..511
            int c   = idx >> 4;          // 32 c-rows
            int p4  = idx & 15;          // 16 float4 per row
            float4 v = *(const float4*)&x[(((b << 5) + c) << 12) + pos0 + (p4 << 2)];
            tile[c][(p4 << 2) + 0] = v.x;
            tile[c][(p4 << 2) + 1] = v.y;
            tile[c][(p4 << 2) + 2] = v.z;
            tile[c][(p4 << 2) + 3] = v.w;
        }
        __syncthreads();
        #pragma unroll
        for (int it = 0; it < 2; ++it) {
            int idx = t + (it << 8);     // 0..511
            int p   = idx >> 3;          // 64 positions
            int c4  = idx & 7;           // 8 c-quads
            float4 v;
            v.x = tile[(c4 << 2) + 0][p];
            v.y = tile[(c4 << 2) + 1][p];
            v.z = tile[(c4 << 2) + 2][p];
            v.w = tile[(c4 << 2) + 3][p];
            *(float4*)&xf[(((b << 12) + pos0 + p) << 5) + (c4 << 2)] = v;
        }
    } else {
        int tid = (bid - 512) * 256 + threadIdx.x;   // 0..16383
        int r = tid >> 6, c = tid & 63;
        float f  = Wu[tid];
        short hi = f2bfs(f);
        short lo = f2bfs(f - bfs2f(hi));
        int s = r >> 5, r5 = r & 31, kg = r5 >> 3, j = r5 & 7;
        int base = ((((s << 2) + kg) << 6) | c) << 4;
        bs[base + j]     = hi;
        bs[base + 8 + j] = lo;
    }
}

__global__ __launch_bounds__(512, 6) void fused2v(
    const float* __restrict__ x,   const float* __restrict__ xf,
    const float* __restrict__ W1,  const float* __restrict__ b1,
    const float* __restrict__ W2,  const float* __restrict__ b2,
    const float* __restrict__ Wu,  const short* __restrict__ bs,
    const float* __restrict__ bu,
    const int*  __restrict__ gidx, const int* __restrict__ loff,
    float*      __restrict__ out,  int use_ws)
{
    // LDS map (round-9/11/14/16 green):
    //   [0,16640)    : sFeat f32[16][260]   (P5/P6) -- overlays sInp/sH/sP
    //     [0,2176)     : sInp f32[16][34]   (P1-P2)
    //     [2176,10368) : sH   f32[16][128]  (P2-P3)
    //     [10368,11904): sP   f32[16][24]   (P3-P4)
    //   [16640,22784): sFlat i32[16][8][12]
    //   [22784,28928): sProp f32[16][8][12]
    //   [28928,29440): sInv  f32[16][8]
    //   [29440,33536): sPart f32[256][4]    (P6 cross-wave partial acc)
    //   [33536,46208): sW2T  f32[24][132]   (W2 transposed, staged in P1;
    //     round-17 test proved global/L1 W2T reads regress P3 by ~11 µs —
    //     the gather stream thrashes L1, LDS staging is the right design)
    __shared__ __align__(16) char lds[46208];
    float* sFeat = (float*)lds;
    float* sInp  = (float*)lds;
    float* sH    = (float*)(lds + 2176);
    float* sP    = (float*)(lds + 10368);
    int*   sFlat = (int*)  (lds + 16640);
    float* sProp = (float*)(lds + 22784);
    float* sInv  = (float*)(lds + 28928);
    float* sPart = (float*)(lds + 29440);
    float* sW2T  = (float*)(lds + 33536);

    const int t    = threadIdx.x;
    const int w    = t >> 6;        // wave 0..7 (two pixels each)
    const int wl   = t & 63;
    const int pix0 = blockIdx.x * PXB;
    const int b    = pix0 >> 12;
    const int rem0 = pix0 & 4095;   // 16 consecutive pixels, same b
    const int w2   = w << 1;        // first local pixel of this wave

    // ---- P1: cooperative staging (inputs + W2 transpose) ----
    {
        int c  = t & 31;
        int lp = t >> 5;            // 0..15
        int rem = rem0 + lp;
        sInp[lp * ADIN + c] = use_ws ? xf[(((b << 12) + rem) << 5) + c]
                                     : x[(((b << 5) + c) << 12) + rem];
        if (t < PXB) {
            int rem2 = rem0 + t;
            sInp[t * ADIN + 32] = (float)(rem2 >> 6) / 63.0f;
            sInp[t * ADIN + 33] = (float)(rem2 & 63) / 63.0f;
        }
        // W2 (128,24) -> sW2T[o][u], 3072 elements, 6 per thread, coalesced reads
        #pragma unroll
        for (int i = 0; i < 6; ++i) {
            int idx = t + (i << 9);
            int u = idx / 24;
            int o = idx - u * 24;
            sW2T[o * W2S + u] = W2[idx];
        }
    }
    __syncthreads();

    // ---- P2: hidden = relu(inp @ W1 + b1), 2 pixels/wave ----
    // FROZEN FORM: scalar W1 loads, sequential fmaf chain. Rounds 12/13
    // proved any load-shape restructure here perturbs codegen (fast-math
    // reassociation) -> sP drift -> floor flips -> absmax ~0.86. Do not touch.
    {
        float h0[2], h1[2];
        float bb0 = b1[wl], bb1 = b1[wl + 64];
        #pragma unroll
        for (int q = 0; q < 2; ++q) { h0[q] = bb0; h1[q] = bb1; }
        #pragma unroll 2
        for (int a = 0; a < ADIN; ++a) {
            float wa = W1[a * HIDDEN + wl];
            float wb = W1[a * HIDDEN + wl + 64];
            #pragma unroll
            for (int q = 0; q < 2; ++q) {
                float iv = sInp[(w2 + q) * ADIN + a];
                h0[q] = fmaf(iv, wa, h0[q]);
                h1[q] = fmaf(iv, wb, h1[q]);
            }
        }
        #pragma unroll
        for (int q = 0; q < 2; ++q) {
            sH[(w2 + q) * HIDDEN + wl]      = fmaxf(h0[q], 0.f);
            sH[(w2 + q) * HIDDEN + wl + 64] = fmaxf(h1[q], 0.f);
        }
    }
    // sH rows wave-private: in-wave LDS ordering suffices (round-5/8/9/11-proven)

    // ---- P3: params = hidden @ W2 + b2; float4 LDS reads (round-9-proven) ----
    // FROZEN FORM: sequential single accumulator. sP feeds floorf().
    if (wl < 48) {
        int hi = (wl >= 24) ? 1 : 0;
        int o  = wl - (hi ? 24 : 0);
        int lp = w2 + hi;
        float acc = b2[o];
        const float* wrow = &sW2T[o * W2S];
        const float* hrow = &sH[lp * HIDDEN];
        #pragma unroll 8
        for (int u4 = 0; u4 < 32; ++u4) {
            float4 wv = *(const float4*)&wrow[u4 << 2];
            float4 hv = *(const float4*)&hrow[u4 << 2];
            acc = fmaf(hv.x, wv.x, acc);
            acc = fmaf(hv.y, wv.y, acc);
            acc = fmaf(hv.z, wv.z, acc);
            acc = fmaf(hv.w, wv.w, acc);
        }
        sP[lp * 24 + o] = acc;
    }
    // sP rows wave-private

    const int k   = wl >> 3;
    const int sub = wl & 7;

    // ---- P4: gaussian params, sample indices, props, dup, norm ----
    #pragma unroll
    for (int q = 0; q < 2; ++q) {
        int lp  = w2 + q;
        int rem = rem0 + lp;
        int pix = pix0 + lp;
        int i   = rem >> 6, j = rem & 63;

        float mr0 = sP[lp * 24 + 2 * k];
        float mr1 = sP[lp * 24 + 2 * k + 1];
        float sr  = sP[lp * 24 + 16 + k];

        float mid0 = ((float)i / 63.0f) * 63.0f;
        float mid1 = ((float)j / 63.0f) * 63.0f;
        float m0 = fmodf(mid0 + mr0, 63.0f); if (m0 < 0.f) m0 += 63.0f;
        float m1 = fmodf(mid1 + mr1, 63.0f); if (m1 < 0.f) m1 += 63.0f;

        float sx  = sr + 2.0f;                                     // SIGMA_BOOST
        float spv = fmaxf(sx, 0.f) + log1pf(__expf(-fabsf(sx)));   // softplus
        float sig = ((spv + 0.05f) * 63.0f) * 0.05f;
        float isig = 1.0f / sig;    // continuous path only: div-once, mul-per-z

        int fl0 = (int)floorf(m0);
        int fl1 = (int)floorf(m1);
        const int glb = (pix * KK + k) << 3;
        const int fpb = (lp * KK + k) * VSN;

        #pragma unroll
        for (int tt = 0; tt < 2; ++tt) {
            if (tt == 1 && sub >= 4) break;
            int v = (tt == 0) ? sub : 8 + sub;
            int i0, j0;
            if (v < 4) {
                i0 = (fl0 + (v >> 1)) & 63;
                j0 = (fl1 + (v & 1)) & 63;
            } else if (v < 8) {
                int g = (v - 4) << 1;
                i0 = gidx[glb + g];
                j0 = gidx[glb + g + 1];
            } else {
                int r = (v - 8) << 1;
                i0 = (fl0 + loff[glb + r]     - 8 + 64) & 63;
                j0 = (fl1 + loff[glb + r + 1] - 8 + 64) & 63;
            }
            float z0 = ((float)i0 - m0) * isig;
            float z1 = ((float)j0 - m1) * isig;
            sFlat[fpb + v] = i0 * 64 + j0;
            sProp[fpb + v] = __expf(-0.5f * (z0 * z0 + z1 * z1));
        }
        // dup-zero (in-wave cross-lane, round-5/8/9/11-proven idiom)
        #pragma unroll
        for (int tt = 0; tt < 2; ++tt) {
            if (tt == 1 && sub >= 4) break;
            int v = (tt == 0) ? sub : 8 + sub;
            int f = sFlat[fpb + v];
            bool dup = false;
            for (int v2 = 0; v2 < v; ++v2)
                dup |= (sFlat[fpb + v2] == f);
            if (dup) sProp[fpb + v] = 0.0f;
        }
        if (sub == 0) {
            float s = 0.0f;
            #pragma unroll
            for (int v = 0; v < VSN; ++v) s += sProp[fpb + v];
            sInv[lp * KK + k] = 1.0f / s;
        }
    }
    __syncthreads();   // overlay guard: region-A reads done before sFeat writes

    // ---- P5: gather + weighted sum -> sFeat[lp][k*32+c] ----
    #pragma unroll
    for (int q = 0; q < 2; ++q) {
        int lp  = w2 + q;
        const int fpb = (lp * KK + k) * VSN;
        float isum = sInv[lp * KK + k];
        int c4 = sub << 2;
        float a0 = 0.f, a1 = 0.f, a2 = 0.f, a3 = 0.f;
        #pragma unroll
        for (int v = 0; v < VSN; ++v) {
            float wt = sProp[fpb + v] * isum;
            int p = sFlat[fpb + v];
            if (use_ws) {
                const float4 xv = *(const float4*)&xf[(((b << 12) + p) << 5) + c4];
                a0 = fmaf(wt, xv.x, a0);
                a1 = fmaf(wt, xv.y, a1);
                a2 = fmaf(wt, xv.z, a2);
                a3 = fmaf(wt, xv.w, a3);
            } else {
                const float* xb = x + (((b << 5) + c4) << 12) + p;
                a0 = fmaf(wt, xb[0],       a0);
                a1 = fmaf(wt, xb[1 << 12], a1);
                a2 = fmaf(wt, xb[2 << 12], a2);
                a3 = fmaf(wt, xb[3 << 12], a3);
            }
        }
        float4 fv; fv.x = a0; fv.y = a1; fv.z = a2; fv.w = a3;
        *(float4*)&sFeat[lp * FPAD + (k << 5) + c4] = fv;
    }
    __syncthreads();

    // ---- P6: GEMM split across wave pairs, partials reduced via sPart ----
    {
        const int l15 = wl & 15;
        const int kg  = wl >> 4;
        const int sg  = w >> 2;          // 0: s=0..3, 1: s=4..7
        const int wc  = w & 3;
        const int col = (wc << 4) + l15;
        f32x4 acc = {0.f, 0.f, 0.f, 0.f};
        #pragma unroll 1
        for (int s0 = 0; s0 < 4; ++s0) {
            int s = (sg << 2) + s0;
            const float* ap = &sFeat[l15 * FPAD + (s << 5) + (kg << 3)];
            float fa[8];
            *(float4*)&fa[0] = *(const float4*)(ap);
            *(float4*)&fa[4] = *(const float4*)(ap + 4);
            short8 ah, al;
            #pragma unroll
            for (int jj = 0; jj < 8; ++jj) {
                float f = fa[jj];
                short h = f2bfs(f);
                ah[jj] = h;
                al[jj] = f2bfs(f - bfs2f(h));
            }
            short8 bh, bl;
            if (use_ws) {
                const short8* bp =
                    (const short8*)(bs + (((((s << 2) + kg) << 6) | col) << 4));
                bh = bp[0];
                bl = bp[1];
            } else {
                #pragma unroll
                for (int jj = 0; jj < 8; ++jj) {
                    float f = Wu[(((s << 5) + (kg << 3) + jj) << 6) + col];
                    short h = f2bfs(f);
                    bh[jj] = h;
                    bl[jj] = f2bfs(f - bfs2f(h));
                }
            }
            acc = __builtin_amdgcn_mfma_f32_16x16x32_bf16(ah, bh, acc, 0, 0, 0);
            acc = __builtin_amdgcn_mfma_f32_16x16x32_bf16(ah, bl, acc, 0, 0, 0);
            acc = __builtin_amdgcn_mfma_f32_16x16x32_bf16(al, bh, acc, 0, 0, 0);
        }
        if (sg == 1)
            *(f32x4*)&sPart[(t - 256) << 2] = acc;
        __syncthreads();   // uniform: all 512 threads reach this
        if (sg == 0) {
            const f32x4 other = *(const f32x4*)&sPart[t << 2];
            float bub = bu[col];
            float4 ov;
            ov.x = acc[0] + other[0] + bub;
            ov.y = acc[1] + other[1] + bub;
            ov.z = acc[2] + other[2] + bub;
            ov.w = acc[3] + other[3] + bub;
            *(float4*)&out[(((b << 6) + col) << 12) + rem0 + (kg << 2)] = ov;
        }
    }
}

extern "C" void kernel_launch(void* const* d_in, const int* in_sizes, int n_in,
                              void* d_out, int out_size, void* d_ws, size_t ws_size,
                              hipStream_t stream) {
    const float* x    = (const float*)d_in[0];
    const float* W1   = (const float*)d_in[1];
    const float* b1   = (const float*)d_in[2];
    const float* W2   = (const float*)d_in[3];
    const float* b2   = (const float*)d_in[4];
    const float* Wu   = (const float*)d_in[5];
    const float* bu   = (const float*)d_in[6];
    const int*   gidx = (const int*)d_in[7];
    const int*   loff = (const int*)d_in[8];
    float* outp = (float*)d_out;

    const size_t xf_bytes = (size_t)BB * HH * WW * CINC * 4;   // 4 MiB
    const size_t bs_bytes = (size_t)256 * 64 * 2 * 2;          // 64 KiB
    int use_ws = (ws_size >= xf_bytes + bs_bytes) ? 1 : 0;
    float* xfp = (float*)d_ws;
    short* bsp = (short*)((char*)d_ws + xf_bytes);

    if (use_ws) {
        // fused prep: 512 tiled-transpose blocks + 64 pack_wu blocks
        prep_all<<<512 + 64, 256, 0, stream>>>(x, Wu, xfp, bsp);
    }
    fused2v<<<(BB * HH * WW) / PXB, 512, 0, stream>>>(
        x, xfp, W1, b1, W2, b2, Wu, bsp, bu, gidx, loff, outp, use_ws);
}

// Round 19
// 77.057 us; speedup vs baseline: 1.1710x; 1.0174x over previous
//
#include <hip/hip_runtime.h>
#include <hip/hip_bf16.h>
#include <math.h>

#define BB 8
#define HH 64
#define WW 64
#define CINC 32
#define COUTC 64
#define KK 8
#define VSN 12
#define HIDDEN 128
#define ADIN 34
#define PXB 16           // pixels per block
#define FPAD 260         // sFeat row stride (floats); arena stride = 2*260
#define AST 520          // per-wave arena stride (floats) = 2080 B
#define W2S 132          // padded W2T row stride (floats)

typedef short short8 __attribute__((ext_vector_type(8)));
typedef float f32x4 __attribute__((ext_vector_type(4)));

__device__ __forceinline__ short f2bfs(float f) {
    __hip_bfloat16 h = __float2bfloat16(f);   // RNE
    return __builtin_bit_cast(short, h);
}
__device__ __forceinline__ float bfs2f(short s) {
    return __bfloat162float(__builtin_bit_cast(__hip_bfloat16, s));
}

// Fused prep:
//   blocks [0,512)   : tiled transpose x (B,CIN,H,W) -> xf (B,HW,CIN)
//   blocks [512,576) : split Wu into bf16 hi/lo MFMA-B-fragment order
__global__ __launch_bounds__(256) void prep_all(const float* __restrict__ x,
                                                const float* __restrict__ Wu,
                                                float* __restrict__ xf,
                                                short* __restrict__ bs) {
    int bid = blockIdx.x;
    if (bid < 512) {
        __shared__ float tile[32][65];   // +1 pad
        int b    = bid >> 6;             // 8 b
        int pos0 = (bid & 63) << 6;      // 64-pos tile
        int t    = threadIdx.x;
        #pragma unroll
        for (int it = 0; it < 2; ++it) {
            int idx = t + (it << 8);
            int c   = idx >> 4;
            int p4  = idx & 15;
            float4 v = *(const float4*)&x[(((b << 5) + c) << 12) + pos0 + (p4 << 2)];
            tile[c][(p4 << 2) + 0] = v.x;
            tile[c][(p4 << 2) + 1] = v.y;
            tile[c][(p4 << 2) + 2] = v.z;
            tile[c][(p4 << 2) + 3] = v.w;
        }
        __syncthreads();
        #pragma unroll
        for (int it = 0; it < 2; ++it) {
            int idx = t + (it << 8);
            int p   = idx >> 3;
            int c4  = idx & 7;
            float4 v;
            v.x = tile[(c4 << 2) + 0][p];
            v.y = tile[(c4 << 2) + 1][p];
            v.z = tile[(c4 << 2) + 2][p];
            v.w = tile[(c4 << 2) + 3][p];
            *(float4*)&xf[(((b << 12) + pos0 + p) << 5) + (c4 << 2)] = v;
        }
    } else {
        int tid = (bid - 512) * 256 + threadIdx.x;   // 0..16383
        int r = tid >> 6, c = tid & 63;
        float f  = Wu[tid];
        short hi = f2bfs(f);
        short lo = f2bfs(f - bfs2f(hi));
        int s = r >> 5, r5 = r & 31, kg = r5 >> 3, j = r5 & 7;
        int base = ((((s << 2) + kg) << 6) | c) << 4;
        bs[base + j]     = hi;
        bs[base + 8 + j] = lo;
    }
}

__global__ __launch_bounds__(512, 6) void fused2v(
    const float* __restrict__ x,   const float* __restrict__ xf,
    const float* __restrict__ W1,  const float* __restrict__ b1,
    const float* __restrict__ W2,  const float* __restrict__ b2,
    const float* __restrict__ Wu,  const short* __restrict__ bs,
    const float* __restrict__ bu,
    const int*  __restrict__ gidx, const int* __restrict__ loff,
    float*      __restrict__ out,  int use_ws)
{
    // LDS map (round-16 totals, overlay re-laid per-wave to kill a barrier):
    //   [0,16640)    : 8 arenas x 520 floats (2080 B each). Arena w (wave w):
    //       sInp2 [0,68)    : 2 x 34  (pixels 2w, 2w+1)   P1-P2
    //       sH2   [68,324)  : 2 x 128                      P2-P3
    //       sP2   [324,372) : 2 x 24                       P3-P4
    //       sFeat2[0,520)   : 2 x 260 OVERLAY              P5-P6
    //     sFeat_off(lp) = lp*260 floats -> BYTE-IDENTICAL to prior rounds.
    //     All P2-P5 traffic is wave-private => NO barrier P2..P5 (the old
    //     overlay-guard barrier convoyed 8 waves; round-10 showed ~16 us cost).
    //   [16640,22784): sFlat i32[16][8][12]
    //   [22784,28928): sProp f32[16][8][12]
    //   [28928,29440): sInv  f32[16][8]
    //   [29440,33536): sPart f32[256][4]    (P6 cross-wave partial acc)
    //   [33536,46208): sW2T  f32[24][132]   (staged in P1; round-17 proved
    //     global/L1 W2T regresses ~11 us — gather stream thrashes L1)
    __shared__ __align__(16) char lds[46208];
    float* sAr   = (float*)lds;              // arenas (sInp/sH/sP/sFeat)
    float* sFeat = (float*)lds;              // sFeat_off(lp) = lp*FPAD
    int*   sFlat = (int*)  (lds + 16640);
    float* sProp = (float*)(lds + 22784);
    float* sInv  = (float*)(lds + 28928);
    float* sPart = (float*)(lds + 29440);
    float* sW2T  = (float*)(lds + 33536);

    const int t    = threadIdx.x;
    const int w    = t >> 6;        // wave 0..7 (two pixels each)
    const int wl   = t & 63;
    const int pix0 = blockIdx.x * PXB;
    const int b    = pix0 >> 12;
    const int rem0 = pix0 & 4095;   // 16 consecutive pixels, same b
    const int w2   = w << 1;        // first local pixel of this wave

    // ---- P1: cooperative staging (inputs + W2 transpose) ----
    {
        int c  = t & 31;
        int lp = t >> 5;            // 0..15
        int rem = rem0 + lp;
        // sInp(lp) = arena(lp>>1) + (lp&1)*34
        sAr[(lp >> 1) * AST + (lp & 1) * 34 + c] =
            use_ws ? xf[(((b << 12) + rem) << 5) + c]
                   : x[(((b << 5) + c) << 12) + rem];
        if (t < PXB) {
            int rem2 = rem0 + t;
            int ib = (t >> 1) * AST + (t & 1) * 34;
            sAr[ib + 32] = (float)(rem2 >> 6) / 63.0f;
            sAr[ib + 33] = (float)(rem2 & 63) / 63.0f;
        }
        // W2 (128,24) -> sW2T[o][u], 3072 elements, 6 per thread, coalesced reads
        #pragma unroll
        for (int i = 0; i < 6; ++i) {
            int idx = t + (i << 9);
            int u = idx / 24;
            int o = idx - u * 24;
            sW2T[o * W2S + u] = W2[idx];
        }
    }
    __syncthreads();

    // ---- P2: hidden = relu(inp @ W1 + b1), 2 pixels/wave ----
    // FROZEN FORM: scalar W1 loads, sequential fmaf chain (rounds 12/13:
    // load-shape changes here flip floors). Only base addresses differ.
    {
        float h0[2], h1[2];
        float bb0 = b1[wl], bb1 = b1[wl + 64];
        #pragma unroll
        for (int q = 0; q < 2; ++q) { h0[q] = bb0; h1[q] = bb1; }
        const float* inp0 = &sAr[w * AST];        // pixel w2   (q=0)
        const float* inp1 = &sAr[w * AST + 34];   // pixel w2+1 (q=1)
        #pragma unroll 2
        for (int a = 0; a < ADIN; ++a) {
            float wa = W1[a * HIDDEN + wl];
            float wb = W1[a * HIDDEN + wl + 64];
            {
                float iv = inp0[a];
                h0[0] = fmaf(iv, wa, h0[0]);
                h1[0] = fmaf(iv, wb, h1[0]);
            }
            {
                float iv = inp1[a];
                h0[1] = fmaf(iv, wa, h0[1]);
                h1[1] = fmaf(iv, wb, h1[1]);
            }
        }
        #pragma unroll
        for (int q = 0; q < 2; ++q) {
            float* hrow = &sAr[w * AST + 68 + q * 128];
            hrow[wl]      = fmaxf(h0[q], 0.f);
            hrow[wl + 64] = fmaxf(h1[q], 0.f);
        }
    }
    // wave-private: in-wave LDS ordering suffices

    // ---- P3: params = hidden @ W2 + b2; float4 LDS reads ----
    // FROZEN FORM: sequential single accumulator. sP feeds floorf().
    if (wl < 48) {
        int hi = (wl >= 24) ? 1 : 0;
        int o  = wl - (hi ? 24 : 0);
        float acc = b2[o];
        const float* wrow = &sW2T[o * W2S];
        const float* hrow = &sAr[w * AST + 68 + hi * 128];
        #pragma unroll 8
        for (int u4 = 0; u4 < 32; ++u4) {
            float4 wv = *(const float4*)&wrow[u4 << 2];
            float4 hv = *(const float4*)&hrow[u4 << 2];
            acc = fmaf(hv.x, wv.x, acc);
            acc = fmaf(hv.y, wv.y, acc);
            acc = fmaf(hv.z, wv.z, acc);
            acc = fmaf(hv.w, wv.w, acc);
        }
        sAr[w * AST + 324 + hi * 24 + o] = acc;
    }
    // wave-private

    const int k   = wl >> 3;
    const int sub = wl & 7;

    // ---- P4: gaussian params, sample indices, props, dup, norm ----
    #pragma unroll
    for (int q = 0; q < 2; ++q) {
        int lp  = w2 + q;
        int rem = rem0 + lp;
        int pix = pix0 + lp;
        int i   = rem >> 6, j = rem & 63;

        const float* sPq = &sAr[w * AST + 324 + q * 24];
        float mr0 = sPq[2 * k];
        float mr1 = sPq[2 * k + 1];
        float sr  = sPq[16 + k];

        float mid0 = ((float)i / 63.0f) * 63.0f;
        float mid1 = ((float)j / 63.0f) * 63.0f;
        float m0 = fmodf(mid0 + mr0, 63.0f); if (m0 < 0.f) m0 += 63.0f;
        float m1 = fmodf(mid1 + mr1, 63.0f); if (m1 < 0.f) m1 += 63.0f;

        float sx  = sr + 2.0f;                                     // SIGMA_BOOST
        float spv = fmaxf(sx, 0.f) + log1pf(__expf(-fabsf(sx)));   // softplus
        float sig = ((spv + 0.05f) * 63.0f) * 0.05f;
        float isig = 1.0f / sig;    // continuous path only

        int fl0 = (int)floorf(m0);
        int fl1 = (int)floorf(m1);
        const int glb = (pix * KK + k) << 3;
        const int fpb = (lp * KK + k) * VSN;

        #pragma unroll
        for (int tt = 0; tt < 2; ++tt) {
            if (tt == 1 && sub >= 4) break;
            int v = (tt == 0) ? sub : 8 + sub;
            int i0, j0;
            if (v < 4) {
                i0 = (fl0 + (v >> 1)) & 63;
                j0 = (fl1 + (v & 1)) & 63;
            } else if (v < 8) {
                int g = (v - 4) << 1;
                i0 = gidx[glb + g];
                j0 = gidx[glb + g + 1];
            } else {
                int r = (v - 8) << 1;
                i0 = (fl0 + loff[glb + r]     - 8 + 64) & 63;
                j0 = (fl1 + loff[glb + r + 1] - 8 + 64) & 63;
            }
            float z0 = ((float)i0 - m0) * isig;
            float z1 = ((float)j0 - m1) * isig;
            sFlat[fpb + v] = i0 * 64 + j0;
            sProp[fpb + v] = __expf(-0.5f * (z0 * z0 + z1 * z1));
        }
        // dup-zero (in-wave cross-lane, proven idiom)
        #pragma unroll
        for (int tt = 0; tt < 2; ++tt) {
            if (tt == 1 && sub >= 4) break;
            int v = (tt == 0) ? sub : 8 + sub;
            int f = sFlat[fpb + v];
            bool dup = false;
            for (int v2 = 0; v2 < v; ++v2)
                dup |= (sFlat[fpb + v2] == f);
            if (dup) sProp[fpb + v] = 0.0f;
        }
        if (sub == 0) {
            float s = 0.0f;
            #pragma unroll
            for (int v = 0; v < VSN; ++v) s += sProp[fpb + v];
            sInv[lp * KK + k] = 1.0f / s;
        }
    }
    // NO barrier: this wave's sInp/sH/sP are dead; sFeat rows about to be
    // written live in THIS wave's arena only (per-wave overlay).

    // ---- P5: gather + weighted sum -> sFeat[lp][k*32+c] ----
    #pragma unroll
    for (int q = 0; q < 2; ++q) {
        int lp  = w2 + q;
        const int fpb = (lp * KK + k) * VSN;
        float isum = sInv[lp * KK + k];
        int c4 = sub << 2;
        float a0 = 0.f, a1 = 0.f, a2 = 0.f, a3 = 0.f;
        #pragma unroll
        for (int v = 0; v < VSN; ++v) {
            float wt = sProp[fpb + v] * isum;
            int p = sFlat[fpb + v];
            if (use_ws) {
                const float4 xv = *(const float4*)&xf[(((b << 12) + p) << 5) + c4];
                a0 = fmaf(wt, xv.x, a0);
                a1 = fmaf(wt, xv.y, a1);
                a2 = fmaf(wt, xv.z, a2);
                a3 = fmaf(wt, xv.w, a3);
            } else {
                const float* xb = x + (((b << 5) + c4) << 12) + p;
                a0 = fmaf(wt, xb[0],       a0);
                a1 = fmaf(wt, xb[1 << 12], a1);
                a2 = fmaf(wt, xb[2 << 12], a2);
                a3 = fmaf(wt, xb[3 << 12], a3);
            }
        }
        float4 fv; fv.x = a0; fv.y = a1; fv.z = a2; fv.w = a3;
        *(float4*)&sFeat[lp * FPAD + (k << 5) + c4] = fv;
    }
    __syncthreads();   // cross-wave: P6 reads all pixels' sFeat rows

    // ---- P6: GEMM split across wave pairs, partials reduced via sPart ----
    {
        const int l15 = wl & 15;
        const int kg  = wl >> 4;
        const int sg  = w >> 2;          // 0: s=0..3, 1: s=4..7
        const int wc  = w & 3;
        const int col = (wc << 4) + l15;
        f32x4 acc = {0.f, 0.f, 0.f, 0.f};
        #pragma unroll 1
        for (int s0 = 0; s0 < 4; ++s0) {
            int s = (sg << 2) + s0;
            const float* ap = &sFeat[l15 * FPAD + (s << 5) + (kg << 3)];
            float fa[8];
            *(float4*)&fa[0] = *(const float4*)(ap);
            *(float4*)&fa[4] = *(const float4*)(ap + 4);
            short8 ah, al;
            #pragma unroll
            for (int jj = 0; jj < 8; ++jj) {
                float f = fa[jj];
                short h = f2bfs(f);
                ah[jj] = h;
                al[jj] = f2bfs(f - bfs2f(h));
            }
            short8 bh, bl;
            if (use_ws) {
                const short8* bp =
                    (const short8*)(bs + (((((s << 2) + kg) << 6) | col) << 4));
                bh = bp[0];
                bl = bp[1];
            } else {
                #pragma unroll
                for (int jj = 0; jj < 8; ++jj) {
                    float f = Wu[(((s << 5) + (kg << 3) + jj) << 6) + col];
                    short h = f2bfs(f);
                    bh[jj] = h;
                    bl[jj] = f2bfs(f - bfs2f(h));
                }
            }
            acc = __builtin_amdgcn_mfma_f32_16x16x32_bf16(ah, bh, acc, 0, 0, 0);
            acc = __builtin_amdgcn_mfma_f32_16x16x32_bf16(ah, bl, acc, 0, 0, 0);
            acc = __builtin_amdgcn_mfma_f32_16x16x32_bf16(al, bh, acc, 0, 0, 0);
        }
        if (sg == 1)
            *(f32x4*)&sPart[(t - 256) << 2] = acc;
        __syncthreads();   // uniform: all 512 threads reach this
        if (sg == 0) {
            const f32x4 other = *(const f32x4*)&sPart[t << 2];
            float bub = bu[col];
            float4 ov;
            ov.x = acc[0] + other[0] + bub;
            ov.y = acc[1] + other[1] + bub;
            ov.z = acc[2] + other[2] + bub;
            ov.w = acc[3] + other[3] + bub;
            *(float4*)&out[(((b << 6) + col) << 12) + rem0 + (kg << 2)] = ov;
        }
    }
}

extern "C" void kernel_launch(void* const* d_in, const int* in_sizes, int n_in,
                              void* d_out, int out_size, void* d_ws, size_t ws_size,
                              hipStream_t stream) {
    const float* x    = (const float*)d_in[0];
    const float* W1   = (const float*)d_in[1];
    const float* b1   = (const float*)d_in[2];
    const float* W2   = (const float*)d_in[3];
    const float* b2   = (const float*)d_in[4];
    const float* Wu   = (const float*)d_in[5];
    const float* bu   = (const float*)d_in[6];
    const int*   gidx = (const int*)d_in[7];
    const int*   loff = (const int*)d_in[8];
    float* outp = (float*)d_out;

    const size_t xf_bytes = (size_t)BB * HH * WW * CINC * 4;   // 4 MiB
    const size_t bs_bytes = (size_t)256 * 64 * 2 * 2;          // 64 KiB
    int use_ws = (ws_size >= xf_bytes + bs_bytes) ? 1 : 0;
    float* xfp = (float*)d_ws;
    short* bsp = (short*)((char*)d_ws + xf_bytes);

    if (use_ws) {
        // fused prep: 512 tiled-transpose blocks + 64 pack_wu blocks
        prep_all<<<512 + 64, 256, 0, stream>>>(x, Wu, xfp, bsp);
    }
    fused2v<<<(BB * HH * WW) / PXB, 512, 0, stream>>>(
        x, xfp, W1, b1, W2, b2, Wu, bsp, bu, gidx, loff, outp, use_ws);
}